// Round 2
// baseline (13627.950 us; speedup 1.0000x reference)
//
#include <hip/hip_runtime.h>
#include <math.h>

#define TT 1024
#define NB 64
#define NSTEPS 16
#define CH 16
#define SMC 10
#define NCLS 10
#define JIT 1e-4f

// ---------------- Btask = W W^T + diag(softplus(v)) ----------------
__global__ __launch_bounds__(256) void k_btask(const float* __restrict__ W,
                                               const float* __restrict__ v,
                                               float* __restrict__ Bt) {
    int t = threadIdx.x;
    for (int e = t; e < 17 * 17; e += 256) {
        int i = e / 17, j = e % 17;
        float s = 0.f;
        for (int r = 0; r < 3; r++) s += W[i * 3 + r] * W[j * 3 + r];
        if (i == j) s += log1pf(expf(v[i]));
        Bt[e] = s;
    }
}

// ---------------- Kxx build (lower 128-blocks) ----------------
__global__ __launch_bounds__(256) void k_build_kxx(const float* __restrict__ x,
                                                   const int* __restrict__ itr,
                                                   const float* __restrict__ lsp,
                                                   const float* __restrict__ noisep,
                                                   const float* __restrict__ Bt,
                                                   float* __restrict__ A, int b0) {
    int bi = blockIdx.x, bj = blockIdx.y, bz = blockIdx.z;
    if (bj > bi) return;
    int b = b0 + bz;
    __shared__ float sxi[128], sxj[128], Btl[289];
    __shared__ int sii[128], sij[128];
    int t = threadIdx.x;
    if (t < 128) { sxi[t] = x[b * TT + bi * 128 + t]; sii[t] = itr[b * TT + bi * 128 + t]; }
    else { int u = t - 128; sxj[u] = x[b * TT + bj * 128 + u]; sij[u] = itr[b * TT + bj * 128 + u]; }
    for (int e = t; e < 289; e += 256) Btl[e] = Bt[e];
    __syncthreads();
    float invls = 1.0f / lsp[0];
    float n2 = noisep[0] * noisep[0] + JIT;
    float* Ab = A + (size_t)bz * TT * TT;
    for (int l = 0; l < 64; l++) {
        int e = l * 256 + t;
        int r = e >> 7, c = e & 127;
        float d = (sxi[r] - sxj[c]) * invls;
        float kv = expf(-0.5f * d * d) * Btl[sii[r] * 17 + sij[c]];
        int gi = bi * 128 + r, gj = bj * 128 + c;
        if (gi == gj) kv += n2;
        Ab[(size_t)gi * TT + gj] = kv;
    }
}

// ---------------- G = Ksx^T build ([train j][test i]) ----------------
__global__ __launch_bounds__(256) void k_build_g(const float* __restrict__ xs,
                                                 const float* __restrict__ x,
                                                 const int* __restrict__ ite,
                                                 const int* __restrict__ itr,
                                                 const float* __restrict__ lsp,
                                                 const float* __restrict__ Bt,
                                                 float* __restrict__ G, int b0) {
    int bj = blockIdx.x, bi = blockIdx.y, bz = blockIdx.z;
    int b = b0 + bz;
    __shared__ float sxr[128], sxc[128], Btl[289];
    __shared__ int sir[128], sic[128];
    int t = threadIdx.x;
    if (t < 128) { sxr[t] = x[b * TT + bj * 128 + t]; sir[t] = itr[b * TT + bj * 128 + t]; }
    else { int u = t - 128; sxc[u] = xs[b * TT + bi * 128 + u]; sic[u] = ite[b * TT + bi * 128 + u]; }
    for (int e = t; e < 289; e += 256) Btl[e] = Bt[e];
    __syncthreads();
    float invls = 1.0f / lsp[0];
    float* Gb = G + (size_t)bz * TT * TT;
    for (int l = 0; l < 64; l++) {
        int e = l * 256 + t;
        int r = e >> 7, c = e & 127;
        float d = (sxc[c] - sxr[r]) * invls;
        float kv = expf(-0.5f * d * d) * Btl[sic[c] * 17 + sir[r]];
        Gb[(size_t)(bj * 128 + r) * TT + bi * 128 + c] = kv;
    }
}

// ---------------- fused Cholesky step: diag factor (+ panel TRSM) ----------------
// block bx==0 writes factored diag; bx>=1 TRSMs trailing panel bx (factors diag
// redundantly in LDS -- cheap and removes a kernel + dependency gap per step).
__global__ __launch_bounds__(64) void k_chol_step(float* __restrict__ A, int k) {
    int bx = blockIdx.x, bz = blockIdx.y;
    float* Ab = A + (size_t)bz * TT * TT;
    int kb = k * NB;
    __shared__ float Ld[NB][NB + 1];
    __shared__ float invl[NB];
    int t = threadIdx.x;
    for (int l = 0; l < NB; l++) Ld[l][t] = Ab[(size_t)(kb + l) * TT + kb + t];
    __syncthreads();
    for (int j = 0; j < NB; j++) {
        if (t == j) { float d = sqrtf(Ld[j][j]); Ld[j][j] = d; invl[j] = 1.0f / d; }
        __syncthreads();
        if (t > j) Ld[t][j] *= invl[j];
        __syncthreads();
        if (t > j) {
            float lij = Ld[t][j];
            for (int p = j + 1; p <= t; p++) Ld[t][p] -= lij * Ld[p][j];
        }
        __syncthreads();
    }
    if (bx == 0) {
        for (int l = 0; l < NB; l++) Ab[(size_t)(kb + l) * TT + kb + t] = Ld[l][t];
        return;
    }
    int r0 = kb + NB * bx;
    __shared__ float RW[NB][NB + 1];
    for (int l = 0; l < NB; l++) RW[l][t] = Ab[(size_t)(r0 + l) * TT + kb + t];
    __syncthreads();
    // thread t owns row t of the panel; forward substitution vs factored Ld
    for (int j = 0; j < NB; j++) {
        float xv = RW[t][j] * invl[j];
        RW[t][j] = xv;
        for (int p = j + 1; p < NB; p++) RW[t][p] -= Ld[p][j] * xv;
    }
    __syncthreads();
    for (int l = 0; l < NB; l++) Ab[(size_t)(r0 + l) * TT + kb + t] = RW[l][t];
}

// ---------------- Cholesky trailing SYRK: 128x128 tiles, K=64 ----------------
__global__ __launch_bounds__(256) void k_syrk128(float* __restrict__ A, int k) {
    int ti = blockIdx.x, tj = blockIdx.y, bz = blockIdx.z;
    if (tj > ti) return;
    float* Ab = A + (size_t)bz * TT * TT;
    int kb = k * NB;
    int base = kb + NB;
    int r0 = base + ti * 128, c0 = base + tj * 128;
    int rvi = TT - r0; if (rvi > 128) rvi = 128;
    int rvj = TT - c0; if (rvj > 128) rvj = 128;
    __shared__ __align__(16) float At[32][132];
    __shared__ __align__(16) float Bs[32][132];
    int t = threadIdx.x;
    int tx = t & 15, ty = t >> 4;
    float acc[8][8] = {};
    for (int s = 0; s < 2; s++) {
        int k0 = kb + s * 32;
        __syncthreads();
        for (int l = 0; l < 4; l++) {
            int f = l * 256 + t;
            int r = f >> 3, c4 = (f & 7) * 4;
            float4 va = make_float4(0.f, 0.f, 0.f, 0.f), vb = make_float4(0.f, 0.f, 0.f, 0.f);
            if (r < rvi) va = *reinterpret_cast<const float4*>(&Ab[(size_t)(r0 + r) * TT + k0 + c4]);
            if (r < rvj) vb = *reinterpret_cast<const float4*>(&Ab[(size_t)(c0 + r) * TT + k0 + c4]);
            At[c4 + 0][r] = va.x; At[c4 + 1][r] = va.y; At[c4 + 2][r] = va.z; At[c4 + 3][r] = va.w;
            Bs[c4 + 0][r] = vb.x; Bs[c4 + 1][r] = vb.y; Bs[c4 + 2][r] = vb.z; Bs[c4 + 3][r] = vb.w;
        }
        __syncthreads();
#pragma unroll 4
        for (int p = 0; p < 32; p++) {
            float4 a0 = *reinterpret_cast<const float4*>(&At[p][ty * 8]);
            float4 a1 = *reinterpret_cast<const float4*>(&At[p][ty * 8 + 4]);
            float4 b0 = *reinterpret_cast<const float4*>(&Bs[p][tx * 8]);
            float4 b1 = *reinterpret_cast<const float4*>(&Bs[p][tx * 8 + 4]);
            float aa[8] = {a0.x, a0.y, a0.z, a0.w, a1.x, a1.y, a1.z, a1.w};
            float bb[8] = {b0.x, b0.y, b0.z, b0.w, b1.x, b1.y, b1.z, b1.w};
            for (int i = 0; i < 8; i++)
                for (int j = 0; j < 8; j++) acc[i][j] += aa[i] * bb[j];
        }
    }
    if (tx * 8 >= rvj) return;
    for (int i = 0; i < 8; i++) {
        int rr = ty * 8 + i;
        if (rr >= rvi) break;
        float* cp = &Ab[(size_t)(r0 + rr) * TT + c0 + tx * 8];
        float4 cv0 = *reinterpret_cast<float4*>(cp);
        float4 cv1 = *reinterpret_cast<float4*>(cp + 4);
        cv0.x -= acc[i][0]; cv0.y -= acc[i][1]; cv0.z -= acc[i][2]; cv0.w -= acc[i][3];
        cv1.x -= acc[i][4]; cv1.y -= acc[i][5]; cv1.z -= acc[i][6]; cv1.w -= acc[i][7];
        *reinterpret_cast<float4*>(cp) = cv0;
        *reinterpret_cast<float4*>(cp + 4) = cv1;
    }
}

// ---------------- big TRSM: diag solve (64 rows of G, all 1024 cols) ----------------
__global__ __launch_bounds__(256) void k_trsm_diag(const float* __restrict__ A,
                                                   float* __restrict__ G, int k) {
    int bz = blockIdx.y;
    const float* Ab = A + (size_t)bz * TT * TT;
    float* Gb = G + (size_t)bz * TT * TT;
    int kb = k * NB;
    __shared__ float Ld[NB][NB + 1];
    __shared__ float invd[NB];
    int t = threadIdx.x;
    for (int l = 0; l < 16; l++) {
        int e = l * 256 + t; int r = e >> 6, c = e & 63;
        Ld[r][c] = Ab[(size_t)(kb + r) * TT + kb + c];
    }
    __syncthreads();
    if (t < NB) invd[t] = 1.0f / Ld[t][t];
    __syncthreads();
    int cidx = blockIdx.x * 256 + t;
    float x[NB];
#pragma unroll
    for (int j = 0; j < NB; j++) x[j] = Gb[(size_t)(kb + j) * TT + cidx];
#pragma unroll
    for (int j = 0; j < NB; j++) {
        float s = x[j];
#pragma unroll
        for (int p = 0; p < j; p++) s -= Ld[j][p] * x[p];
        x[j] = s * invd[j];
    }
#pragma unroll
    for (int j = 0; j < NB; j++) Gb[(size_t)(kb + j) * TT + cidx] = x[j];
}

// ---------------- big TRSM trailing GEMM: 128x128 tiles, K=64 ----------------
__global__ __launch_bounds__(256) void k_gemm_update128(const float* __restrict__ A,
                                                        float* __restrict__ G, int k) {
    int ti = blockIdx.x, tjc = blockIdx.y, bz = blockIdx.z;
    const float* Ab = A + (size_t)bz * TT * TT;
    float* Gb = G + (size_t)bz * TT * TT;
    int kb = k * NB;
    int r0 = kb + NB + ti * 128;
    int c0 = tjc * 128;
    int rvi = TT - r0; if (rvi > 128) rvi = 128;
    __shared__ __align__(16) float At[32][132];
    __shared__ __align__(16) float Bs[32][132];
    int t = threadIdx.x, tx = t & 15, ty = t >> 4;
    float acc[8][8] = {};
    for (int s = 0; s < 2; s++) {
        int k0 = kb + s * 32;
        __syncthreads();
        for (int l = 0; l < 4; l++) {
            int f = l * 256 + t;
            int r = f >> 3, c4 = (f & 7) * 4;
            float4 va = make_float4(0.f, 0.f, 0.f, 0.f);
            if (r < rvi) va = *reinterpret_cast<const float4*>(&Ab[(size_t)(r0 + r) * TT + k0 + c4]);
            At[c4 + 0][r] = va.x; At[c4 + 1][r] = va.y; At[c4 + 2][r] = va.z; At[c4 + 3][r] = va.w;
            int kr = f >> 5, cc4 = (f & 31) * 4;
            float4 vb = *reinterpret_cast<const float4*>(&Gb[(size_t)(k0 + kr) * TT + c0 + cc4]);
            *reinterpret_cast<float4*>(&Bs[kr][cc4]) = vb;
        }
        __syncthreads();
#pragma unroll 4
        for (int p = 0; p < 32; p++) {
            float4 a0 = *reinterpret_cast<const float4*>(&At[p][ty * 8]);
            float4 a1 = *reinterpret_cast<const float4*>(&At[p][ty * 8 + 4]);
            float4 b0 = *reinterpret_cast<const float4*>(&Bs[p][tx * 8]);
            float4 b1 = *reinterpret_cast<const float4*>(&Bs[p][tx * 8 + 4]);
            float aa[8] = {a0.x, a0.y, a0.z, a0.w, a1.x, a1.y, a1.z, a1.w};
            float bb[8] = {b0.x, b0.y, b0.z, b0.w, b1.x, b1.y, b1.z, b1.w};
            for (int i = 0; i < 8; i++)
                for (int j = 0; j < 8; j++) acc[i][j] += aa[i] * bb[j];
        }
    }
    for (int i = 0; i < 8; i++) {
        int rr = ty * 8 + i;
        if (rr >= rvi) break;
        float* cp = &Gb[(size_t)(r0 + rr) * TT + c0 + tx * 8];
        float4 cv0 = *reinterpret_cast<float4*>(cp);
        float4 cv1 = *reinterpret_cast<float4*>(cp + 4);
        cv0.x -= acc[i][0]; cv0.y -= acc[i][1]; cv0.z -= acc[i][2]; cv0.w -= acc[i][3];
        cv1.x -= acc[i][4]; cv1.y -= acc[i][5]; cv1.z -= acc[i][6]; cv1.w -= acc[i][7];
        *reinterpret_cast<float4*>(cp) = cv0;
        *reinterpret_cast<float4*>(cp + 4) = cv1;
    }
}

// ---------------- fused alpha solve: z = L^{-1}(y-c), alpha = L^{-T} z ----------------
__global__ __launch_bounds__(64) void k_solve(const float* __restrict__ A,
                                              const float* __restrict__ values,
                                              const float* __restrict__ mc,
                                              float* __restrict__ abuf, int b0) {
    int bz = blockIdx.x; int b = b0 + bz;
    const float* Ab = A + (size_t)bz * TT * TT;
    __shared__ float zl[TT];
    __shared__ float Ld[NB][NB + 1];
    __shared__ float invd[NB];
    int t = threadIdx.x;
    float c0 = mc[0];
    for (int i = t; i < TT; i += 64) zl[i] = values[b * TT + i] - c0;
    for (int k = 0; k < NSTEPS; k++) {
        int kb = k * NB;
        __syncthreads();
        for (int l = 0; l < NB; l++) Ld[l][t] = Ab[(size_t)(kb + l) * TT + kb + t];
        __syncthreads();
        invd[t] = 1.0f / Ld[t][t];
        __syncthreads();
        for (int j = 0; j < NB; j++) {
            if (t == j) zl[kb + j] *= invd[j];
            __syncthreads();
            if (t > j) zl[kb + t] -= Ld[t][j] * zl[kb + j];
        }
        __syncthreads();
        for (int r = kb + NB + t; r < TT; r += 64) {
            float acc = 0.f;
            for (int c = 0; c < NB; c++) acc += Ab[(size_t)r * TT + kb + c] * zl[kb + c];
            zl[r] -= acc;
        }
    }
    // backward: alpha = L^{-T} z
    for (int k = NSTEPS - 1; k >= 0; k--) {
        int kb = k * NB;
        __syncthreads();
        for (int l = 0; l < NB; l++) Ld[l][t] = Ab[(size_t)(kb + l) * TT + kb + t];
        __syncthreads();
        invd[t] = 1.0f / Ld[t][t];
        __syncthreads();
        for (int j = NB - 1; j >= 0; j--) {
            if (t == j) zl[kb + j] *= invd[j];
            __syncthreads();
            if (t < j) zl[kb + t] -= Ld[j][t] * zl[kb + j];
        }
        __syncthreads();
        for (int i = t; i < kb; i += 64) {
            float acc = 0.f;
            for (int j = 0; j < NB; j++) acc += Ab[(size_t)(kb + j) * TT + i] * zl[kb + j];
            zl[i] -= acc;
        }
    }
    __syncthreads();
    for (int i = t; i < TT; i += 64) abuf[b * TT + i] = zl[i];
}

// ---------------- mean = c + G^T alpha ----------------
__global__ __launch_bounds__(256) void k_mean(const float* __restrict__ G,
                                              const float* __restrict__ abuf,
                                              const float* __restrict__ mc,
                                              float* __restrict__ meanb, int b0) {
    int bz = blockIdx.y; int b = b0 + bz;
    const float* Gb = G + (size_t)bz * TT * TT;
    int i = blockIdx.x * 256 + threadIdx.x;
    float acc = 0.f;
    for (int j = 0; j < TT; j++) acc += Gb[(size_t)j * TT + i] * abuf[b * TT + j];
    meanb[b * TT + i] = mc[0] + acc;
}

// ---------------- cov = Kss - V^T V + JIT*I : 128x128 tiles ----------------
__global__ __launch_bounds__(256) void k_cov128(const float* __restrict__ G,
                                                const float* __restrict__ xs,
                                                const int* __restrict__ ite,
                                                const float* __restrict__ lsp,
                                                const float* __restrict__ Bt,
                                                float* __restrict__ A, int b0) {
    int ti = blockIdx.x, tj = blockIdx.y, bz = blockIdx.z;
    if (tj > ti) return;
    int b = b0 + bz;
    const float* Gb = G + (size_t)bz * TT * TT;
    float* Ab = A + (size_t)bz * TT * TT;
    int i0 = ti * 128, j0 = tj * 128;
    __shared__ __align__(16) float Va[32][132];
    __shared__ __align__(16) float Vb[32][132];
    __shared__ float sxi[128], sxj[128], Btl[289];
    __shared__ int sei[128], sej[128];
    int t = threadIdx.x, tx = t & 15, ty = t >> 4;
    if (t < 128) { sxi[t] = xs[b * TT + i0 + t]; sei[t] = ite[b * TT + i0 + t]; }
    else { int u = t - 128; sxj[u] = xs[b * TT + j0 + u]; sej[u] = ite[b * TT + j0 + u]; }
    for (int e = t; e < 289; e += 256) Btl[e] = Bt[e];
    float acc[8][8] = {};
    for (int k0 = 0; k0 < TT; k0 += 32) {
        __syncthreads();
        for (int l = 0; l < 4; l++) {
            int f = l * 256 + t;
            int kr = f >> 5, cc4 = (f & 31) * 4;
            *reinterpret_cast<float4*>(&Va[kr][cc4]) =
                *reinterpret_cast<const float4*>(&Gb[(size_t)(k0 + kr) * TT + i0 + cc4]);
            *reinterpret_cast<float4*>(&Vb[kr][cc4]) =
                *reinterpret_cast<const float4*>(&Gb[(size_t)(k0 + kr) * TT + j0 + cc4]);
        }
        __syncthreads();
#pragma unroll 4
        for (int p = 0; p < 32; p++) {
            float4 a0 = *reinterpret_cast<const float4*>(&Va[p][ty * 8]);
            float4 a1 = *reinterpret_cast<const float4*>(&Va[p][ty * 8 + 4]);
            float4 b0 = *reinterpret_cast<const float4*>(&Vb[p][tx * 8]);
            float4 b1 = *reinterpret_cast<const float4*>(&Vb[p][tx * 8 + 4]);
            float aa[8] = {a0.x, a0.y, a0.z, a0.w, a1.x, a1.y, a1.z, a1.w};
            float bb[8] = {b0.x, b0.y, b0.z, b0.w, b1.x, b1.y, b1.z, b1.w};
            for (int i = 0; i < 8; i++)
                for (int j = 0; j < 8; j++) acc[i][j] += aa[i] * bb[j];
        }
    }
    float invls = 1.0f / lsp[0];
    for (int i = 0; i < 8; i++) {
        int ri = ty * 8 + i; int gi = i0 + ri;
        float xi = sxi[ri]; int ci = sei[ri] * 17;
        for (int j = 0; j < 8; j++) {
            int rj = tx * 8 + j; int gj = j0 + rj;
            float d = (xi - sxj[rj]) * invls;
            float v = expf(-0.5f * d * d) * Btl[ci + sej[rj]] - acc[i][j];
            if (gi == gj) v += JIT;
            Ab[(size_t)gi * TT + gj] = v;
        }
    }
}

// ---------------- P[c][j] = sum_{i>=j, ch(i)=c} Lstar[i][j] ----------------
__global__ __launch_bounds__(256) void k_P(const float* __restrict__ A,
                                           const int* __restrict__ ite,
                                           float* __restrict__ P, int b0) {
    int bz = blockIdx.y; int b = b0 + bz;
    const float* Ab = A + (size_t)bz * TT * TT;
    __shared__ int chl[TT];
    __shared__ float accl[CH * 256];
    int t = threadIdx.x;
    for (int i = t; i < TT; i += 256) chl[i] = ite[b * TT + i];
    for (int c = 0; c < CH; c++) accl[c * 256 + t] = 0.f;
    __syncthreads();
    int j0 = blockIdx.x * 256;
    int j = j0 + t;
    for (int i = j0; i < TT; i++) {
        float v = Ab[(size_t)i * TT + j];
        if (i >= j) accl[chl[i] * 256 + t] += v;
    }
    for (int c = 0; c < CH; c++) P[((size_t)b * CH + c) * TT + j] = accl[c * 256 + t];
}

// ---------------- msum[c] = sum_{ch(i)=c} mean[i] ----------------
__global__ __launch_bounds__(64) void k_msum(const float* __restrict__ meanb,
                                             const int* __restrict__ ite,
                                             float* __restrict__ msum, int b0) {
    int bz = blockIdx.x; int b = b0 + bz;
    __shared__ float pacc[CH][65];
    int t = threadIdx.x;
    for (int c = 0; c < CH; c++) pacc[c][t] = 0.f;
    __syncthreads();
    for (int i = t; i < TT; i += 64) pacc[ite[b * TT + i]][t] += meanb[b * TT + i];
    __syncthreads();
    if (t < CH) {
        float s = 0.f;
        for (int u = 0; u < 64; u++) s += pacc[t][u];
        msum[b * CH + t] = s;
    }
}

// ---------------- feat + classifier head ----------------
__global__ __launch_bounds__(256) void k_featout(const float* __restrict__ P,
                                                 const float* __restrict__ msum,
                                                 const float* __restrict__ eps,
                                                 const float* __restrict__ Wc,
                                                 const float* __restrict__ bc,
                                                 float* __restrict__ out, int b0, int Btot) {
    int s = blockIdx.x; int b = b0 + blockIdx.y;
    __shared__ float el[TT];
    __shared__ float part[256];
    __shared__ float featl[CH];
    int t = threadIdx.x;
    for (int i = t; i < TT; i += 256) el[i] = eps[((size_t)s * Btot + b) * TT + i];
    __syncthreads();
    int c = t >> 4, seg = t & 15;
    float acc = 0.f;
    const float* Pr = &P[((size_t)b * CH + c) * TT + seg * 64];
    for (int j = 0; j < 64; j++) acc += Pr[j] * el[seg * 64 + j];
    part[t] = acc;
    __syncthreads();
    if (t < CH) {
        float s2 = msum[b * CH + t];
        for (int g = 0; g < 16; g++) s2 += part[t * 16 + g];
        featl[t] = s2 * (1.0f / 64.0f);
    }
    __syncthreads();
    if (t < NCLS) {
        float o = bc[t];
        for (int c2 = 0; c2 < CH; c2++) o += featl[c2] * Wc[c2 * NCLS + t];
        out[((size_t)s * Btot + b) * NCLS + t] = o;
    }
}

extern "C" void kernel_launch(void* const* d_in, const int* in_sizes, int n_in,
                              void* d_out, int out_size, void* d_ws, size_t ws_size,
                              hipStream_t stream) {
    const float* inputs       = (const float*)d_in[0];
    const float* values       = (const float*)d_in[1];
    const float* test_inputs  = (const float*)d_in[2];
    const float* eps          = (const float*)d_in[3];
    const float* mc           = (const float*)d_in[4];
    const float* ls           = (const float*)d_in[5];
    const float* noise        = (const float*)d_in[6];
    const float* W_task       = (const float*)d_in[7];
    const float* v_task       = (const float*)d_in[8];
    const float* W_clf        = (const float*)d_in[9];
    const float* b_clf        = (const float*)d_in[10];
    const int*   indices      = (const int*)d_in[11];
    const int*   test_indices = (const int*)d_in[12];
    float* out = (float*)d_out;

    int Btot = in_sizes[1] / TT;   // 32

    float* ws = (float*)d_ws;
    size_t off = 0;
    float* Bt    = ws + off; off += 512;
    float* abuf  = ws + off; off += (size_t)Btot * TT;
    float* meanb = ws + off; off += (size_t)Btot * TT;
    float* Pb    = ws + off; off += (size_t)Btot * CH * TT;
    float* msum  = ws + off; off += (size_t)Btot * CH;
    off = (off + 63) & ~(size_t)63;

    size_t avail = (ws_size / 4 > off) ? (ws_size / 4 - off) : 0;
    size_t per = 2 * (size_t)TT * TT;
    int chunk = (int)(avail / per);
    if (chunk < 1) chunk = 1;
    if (chunk > Btot) chunk = Btot;
    float* bigA = ws + off;
    float* bigG = bigA + (size_t)chunk * TT * TT;

    k_btask<<<1, 256, 0, stream>>>(W_task, v_task, Bt);

    for (int b0 = 0; b0 < Btot; b0 += chunk) {
        int bc = chunk; if (b0 + bc > Btot) bc = Btot - b0;

        // ---- Kxx and its Cholesky ----
        k_build_kxx<<<dim3(8, 8, bc), 256, 0, stream>>>(inputs, indices, ls, noise, Bt, bigA, b0);
        for (int k = 0; k < NSTEPS; k++) {
            int m = NSTEPS - 1 - k;
            k_chol_step<<<dim3(m + 1, bc), 64, 0, stream>>>(bigA, k);
            if (m > 0) {
                int nt = (NB * m + 127) / 128;
                k_syrk128<<<dim3(nt, nt, bc), 256, 0, stream>>>(bigA, k);
            }
        }
        // ---- alpha = Kxx^{-1}(y-c) ----
        k_solve<<<bc, 64, 0, stream>>>(bigA, values, mc, abuf, b0);
        // ---- G = Ksx^T, mean ----
        k_build_g<<<dim3(8, 8, bc), 256, 0, stream>>>(test_inputs, inputs, test_indices, indices, ls, Bt, bigG, b0);
        k_mean<<<dim3(4, bc), 256, 0, stream>>>(bigG, abuf, mc, meanb, b0);
        // ---- V = L^{-1} G (in place) ----
        for (int k = 0; k < NSTEPS; k++) {
            k_trsm_diag<<<dim3(4, bc), 256, 0, stream>>>(bigA, bigG, k);
            int m = NSTEPS - 1 - k;
            if (m > 0) {
                int nt = (NB * m + 127) / 128;
                k_gemm_update128<<<dim3(nt, 8, bc), 256, 0, stream>>>(bigA, bigG, k);
            }
        }
        // ---- cov -> A, chol(cov) ----
        k_cov128<<<dim3(8, 8, bc), 256, 0, stream>>>(bigG, test_inputs, test_indices, ls, Bt, bigA, b0);
        for (int k = 0; k < NSTEPS; k++) {
            int m = NSTEPS - 1 - k;
            k_chol_step<<<dim3(m + 1, bc), 64, 0, stream>>>(bigA, k);
            if (m > 0) {
                int nt = (NB * m + 127) / 128;
                k_syrk128<<<dim3(nt, nt, bc), 256, 0, stream>>>(bigA, k);
            }
        }
        // ---- pooled sampling + classifier ----
        k_P<<<dim3(4, bc), 256, 0, stream>>>(bigA, test_indices, Pb, b0);
        k_msum<<<bc, 64, 0, stream>>>(meanb, test_indices, msum, b0);
        k_featout<<<dim3(SMC, bc), 256, 0, stream>>>(Pb, msum, eps, W_clf, b_clf, out, b0, Btot);
    }
}

// Round 3
// 12773.390 us; speedup vs baseline: 1.0669x; 1.0669x over previous
//
#include <hip/hip_runtime.h>
#include <math.h>

#define TT 1024
#define NB 64
#define NSTEPS 16
#define CH 16
#define SMC 10
#define NCLS 10
#define JIT 1e-4f

__device__ __forceinline__ void tri_map(int tau, int& ti, int& tj) {
    int i = 0, r = tau;
    while (r >= i + 1) { r -= i + 1; i++; }
    ti = i; tj = r;
}

// ---------------- Btask = W W^T + diag(softplus(v)) ----------------
__global__ __launch_bounds__(256) void k_btask(const float* __restrict__ W,
                                               const float* __restrict__ v,
                                               float* __restrict__ Bt) {
    int t = threadIdx.x;
    for (int e = t; e < 17 * 17; e += 256) {
        int i = e / 17, j = e % 17;
        float s = 0.f;
        for (int r = 0; r < 3; r++) s += W[i * 3 + r] * W[j * 3 + r];
        if (i == j) s += log1pf(expf(v[i]));
        Bt[e] = s;
    }
}

// ---------------- Kxx build (lower 128-blocks) ----------------
__global__ __launch_bounds__(256) void k_build_kxx(const float* __restrict__ x,
                                                   const int* __restrict__ itr,
                                                   const float* __restrict__ lsp,
                                                   const float* __restrict__ noisep,
                                                   const float* __restrict__ Bt,
                                                   float* __restrict__ A, int b0) {
    int bi = blockIdx.x, bj = blockIdx.y, bz = blockIdx.z;
    if (bj > bi) return;
    int b = b0 + bz;
    __shared__ float sxi[128], sxj[128], Btl[289];
    __shared__ int sii[128], sij[128];
    int t = threadIdx.x;
    if (t < 128) { sxi[t] = x[b * TT + bi * 128 + t]; sii[t] = itr[b * TT + bi * 128 + t]; }
    else { int u = t - 128; sxj[u] = x[b * TT + bj * 128 + u]; sij[u] = itr[b * TT + bj * 128 + u]; }
    for (int e = t; e < 289; e += 256) Btl[e] = Bt[e];
    __syncthreads();
    float invls = 1.0f / lsp[0];
    float n2 = noisep[0] * noisep[0] + JIT;
    float* Ab = A + (size_t)bz * TT * TT;
    for (int l = 0; l < 64; l++) {
        int e = l * 256 + t;
        int r = e >> 7, c = e & 127;
        float d = (sxi[r] - sxj[c]) * invls;
        float kv = expf(-0.5f * d * d) * Btl[sii[r] * 17 + sij[c]];
        int gi = bi * 128 + r, gj = bj * 128 + c;
        if (gi == gj) kv += n2;
        Ab[(size_t)gi * TT + gj] = kv;
    }
}

// ---------------- G = Ksx^T build ([train j][test i]) ----------------
__global__ __launch_bounds__(256) void k_build_g(const float* __restrict__ xs,
                                                 const float* __restrict__ x,
                                                 const int* __restrict__ ite,
                                                 const int* __restrict__ itr,
                                                 const float* __restrict__ lsp,
                                                 const float* __restrict__ Bt,
                                                 float* __restrict__ G, int b0) {
    int bj = blockIdx.x, bi = blockIdx.y, bz = blockIdx.z;
    int b = b0 + bz;
    __shared__ float sxr[128], sxc[128], Btl[289];
    __shared__ int sir[128], sic[128];
    int t = threadIdx.x;
    if (t < 128) { sxr[t] = x[b * TT + bj * 128 + t]; sir[t] = itr[b * TT + bj * 128 + t]; }
    else { int u = t - 128; sxc[u] = xs[b * TT + bi * 128 + u]; sic[u] = ite[b * TT + bi * 128 + u]; }
    for (int e = t; e < 289; e += 256) Btl[e] = Bt[e];
    __syncthreads();
    float invls = 1.0f / lsp[0];
    float* Gb = G + (size_t)bz * TT * TT;
    for (int l = 0; l < 64; l++) {
        int e = l * 256 + t;
        int r = e >> 7, c = e & 127;
        float d = (sxc[c] - sxr[r]) * invls;
        float kv = expf(-0.5f * d * d) * Btl[sic[c] * 17 + sir[r]];
        Gb[(size_t)(bj * 128 + r) * TT + bi * 128 + c] = kv;
    }
}

// ---------------- fused Cholesky step: diag factor (+ panel TRSM) ----------------
__global__ __launch_bounds__(64) void k_chol_step(float* __restrict__ A, int k) {
    int bx = blockIdx.x, bz = blockIdx.y;
    float* Ab = A + (size_t)bz * TT * TT;
    int kb = k * NB;
    __shared__ float Ld[NB][NB + 1];
    __shared__ float invl[NB];
    int t = threadIdx.x;
    for (int l = 0; l < NB; l++) Ld[l][t] = Ab[(size_t)(kb + l) * TT + kb + t];
    __syncthreads();
    for (int j = 0; j < NB; j++) {
        if (t == j) { float d = sqrtf(Ld[j][j]); Ld[j][j] = d; invl[j] = 1.0f / d; }
        __syncthreads();
        if (t > j) Ld[t][j] *= invl[j];
        __syncthreads();
        if (t > j) {
            float lij = Ld[t][j];
            for (int p = j + 1; p <= t; p++) Ld[t][p] -= lij * Ld[p][j];
        }
        __syncthreads();
    }
    if (bx == 0) {
        for (int l = 0; l < NB; l++) Ab[(size_t)(kb + l) * TT + kb + t] = Ld[l][t];
        return;
    }
    int r0 = kb + NB * bx;
    __shared__ float RW[NB][NB + 1];
    for (int l = 0; l < NB; l++) RW[l][t] = Ab[(size_t)(r0 + l) * TT + kb + t];
    __syncthreads();
    for (int j = 0; j < NB; j++) {
        float xv = RW[t][j] * invl[j];
        RW[t][j] = xv;
        for (int p = j + 1; p < NB; p++) RW[t][p] -= Ld[p][j] * xv;
    }
    __syncthreads();
    for (int l = 0; l < NB; l++) Ab[(size_t)(r0 + l) * TT + kb + t] = RW[l][t];
}

// ---------------- Cholesky trailing SYRK: 128x128 tiles, XCD-pinned ----------------
__global__ __launch_bounds__(256) void k_syrk128(float* __restrict__ A, int k, int bc) {
    int lin = blockIdx.x;
    int slot = lin & 7, tau = lin >> 3;
    int beta = ((slot - 4 * (tau & 1)) & 7) + (blockIdx.y << 3);
    if (beta >= bc) return;
    int ti, tj; tri_map(tau, ti, tj);
    float* Ab = A + (size_t)beta * TT * TT;
    int kb = k * NB;
    int base = kb + NB;
    int r0 = base + ti * 128, c0 = base + tj * 128;
    int rvi = TT - r0; if (rvi > 128) rvi = 128;
    int rvj = TT - c0; if (rvj > 128) rvj = 128;
    __shared__ __align__(16) float At[32][132];
    __shared__ __align__(16) float Bs[32][132];
    int t = threadIdx.x;
    int tx = t & 15, ty = t >> 4;
    float acc[8][8] = {};
    for (int s = 0; s < 2; s++) {
        int k0 = kb + s * 32;
        __syncthreads();
        for (int l = 0; l < 4; l++) {
            int f = l * 256 + t;
            int r = f >> 3, c4 = (f & 7) * 4;
            float4 va = make_float4(0.f, 0.f, 0.f, 0.f), vb = make_float4(0.f, 0.f, 0.f, 0.f);
            if (r < rvi) va = *reinterpret_cast<const float4*>(&Ab[(size_t)(r0 + r) * TT + k0 + c4]);
            if (r < rvj) vb = *reinterpret_cast<const float4*>(&Ab[(size_t)(c0 + r) * TT + k0 + c4]);
            At[c4 + 0][r] = va.x; At[c4 + 1][r] = va.y; At[c4 + 2][r] = va.z; At[c4 + 3][r] = va.w;
            Bs[c4 + 0][r] = vb.x; Bs[c4 + 1][r] = vb.y; Bs[c4 + 2][r] = vb.z; Bs[c4 + 3][r] = vb.w;
        }
        __syncthreads();
#pragma unroll 4
        for (int p = 0; p < 32; p++) {
            float4 a0 = *reinterpret_cast<const float4*>(&At[p][ty * 8]);
            float4 a1 = *reinterpret_cast<const float4*>(&At[p][ty * 8 + 4]);
            float4 b0 = *reinterpret_cast<const float4*>(&Bs[p][tx * 4]);
            float4 b1 = *reinterpret_cast<const float4*>(&Bs[p][tx * 4 + 64]);
            float aa[8] = {a0.x, a0.y, a0.z, a0.w, a1.x, a1.y, a1.z, a1.w};
            float bl[4] = {b0.x, b0.y, b0.z, b0.w};
            float bh[4] = {b1.x, b1.y, b1.z, b1.w};
            for (int i = 0; i < 8; i++) {
                for (int j = 0; j < 4; j++) acc[i][j] += aa[i] * bl[j];
                for (int j = 0; j < 4; j++) acc[i][j + 4] += aa[i] * bh[j];
            }
        }
    }
    for (int i = 0; i < 8; i++) {
        int rr = ty * 8 + i;
        if (rr >= rvi) break;
        float* cp0 = &Ab[(size_t)(r0 + rr) * TT + c0 + tx * 4];
        float4 cv0 = *reinterpret_cast<float4*>(cp0);
        cv0.x -= acc[i][0]; cv0.y -= acc[i][1]; cv0.z -= acc[i][2]; cv0.w -= acc[i][3];
        *reinterpret_cast<float4*>(cp0) = cv0;
        if (rvj > 64) {
            float* cp1 = cp0 + 64;
            float4 cv1 = *reinterpret_cast<float4*>(cp1);
            cv1.x -= acc[i][4]; cv1.y -= acc[i][5]; cv1.z -= acc[i][6]; cv1.w -= acc[i][7];
            *reinterpret_cast<float4*>(cp1) = cv1;
        }
    }
}

// ---------------- big TRSM: diag solve (64 rows of G, all 1024 cols) ----------------
__global__ __launch_bounds__(256) void k_trsm_diag(const float* __restrict__ A,
                                                   float* __restrict__ G, int k) {
    int bz = blockIdx.y;
    const float* Ab = A + (size_t)bz * TT * TT;
    float* Gb = G + (size_t)bz * TT * TT;
    int kb = k * NB;
    __shared__ float Ld[NB][NB + 1];
    __shared__ float invd[NB];
    int t = threadIdx.x;
    for (int l = 0; l < 16; l++) {
        int e = l * 256 + t; int r = e >> 6, c = e & 63;
        Ld[r][c] = Ab[(size_t)(kb + r) * TT + kb + c];
    }
    __syncthreads();
    if (t < NB) invd[t] = 1.0f / Ld[t][t];
    __syncthreads();
    int cidx = blockIdx.x * 256 + t;
    float x[NB];
#pragma unroll
    for (int j = 0; j < NB; j++) x[j] = Gb[(size_t)(kb + j) * TT + cidx];
#pragma unroll
    for (int j = 0; j < NB; j++) {
        float s = x[j];
#pragma unroll
        for (int p = 0; p < j; p++) s -= Ld[j][p] * x[p];
        x[j] = s * invd[j];
    }
#pragma unroll
    for (int j = 0; j < NB; j++) Gb[(size_t)(kb + j) * TT + cidx] = x[j];
}

// ---------------- big TRSM trailing GEMM: 128x128 tiles, XCD-pinned ----------------
__global__ __launch_bounds__(256) void k_gemm_update128(const float* __restrict__ A,
                                                        float* __restrict__ G, int k, int bc) {
    int lin = blockIdx.x;
    int slot = lin & 7, tau = lin >> 3;
    int beta = ((slot - 4 * (tau & 1)) & 7) + (blockIdx.y << 3);
    if (beta >= bc) return;
    int ti = tau >> 3, tjc = tau & 7;
    const float* Ab = A + (size_t)beta * TT * TT;
    float* Gb = G + (size_t)beta * TT * TT;
    int kb = k * NB;
    int r0 = kb + NB + ti * 128;
    int c0 = tjc * 128;
    int rvi = TT - r0; if (rvi > 128) rvi = 128;
    __shared__ __align__(16) float At[32][132];
    __shared__ __align__(16) float Bs[32][132];
    int t = threadIdx.x, tx = t & 15, ty = t >> 4;
    float acc[8][8] = {};
    for (int s = 0; s < 2; s++) {
        int k0 = kb + s * 32;
        __syncthreads();
        for (int l = 0; l < 4; l++) {
            int f = l * 256 + t;
            int r = f >> 3, c4 = (f & 7) * 4;
            float4 va = make_float4(0.f, 0.f, 0.f, 0.f);
            if (r < rvi) va = *reinterpret_cast<const float4*>(&Ab[(size_t)(r0 + r) * TT + k0 + c4]);
            At[c4 + 0][r] = va.x; At[c4 + 1][r] = va.y; At[c4 + 2][r] = va.z; At[c4 + 3][r] = va.w;
            int kr = f >> 5, cc4 = (f & 31) * 4;
            float4 vb = *reinterpret_cast<const float4*>(&Gb[(size_t)(k0 + kr) * TT + c0 + cc4]);
            *reinterpret_cast<float4*>(&Bs[kr][cc4]) = vb;
        }
        __syncthreads();
#pragma unroll 4
        for (int p = 0; p < 32; p++) {
            float4 a0 = *reinterpret_cast<const float4*>(&At[p][ty * 8]);
            float4 a1 = *reinterpret_cast<const float4*>(&At[p][ty * 8 + 4]);
            float4 b0 = *reinterpret_cast<const float4*>(&Bs[p][tx * 4]);
            float4 b1 = *reinterpret_cast<const float4*>(&Bs[p][tx * 4 + 64]);
            float aa[8] = {a0.x, a0.y, a0.z, a0.w, a1.x, a1.y, a1.z, a1.w};
            float bl[4] = {b0.x, b0.y, b0.z, b0.w};
            float bh[4] = {b1.x, b1.y, b1.z, b1.w};
            for (int i = 0; i < 8; i++) {
                for (int j = 0; j < 4; j++) acc[i][j] += aa[i] * bl[j];
                for (int j = 0; j < 4; j++) acc[i][j + 4] += aa[i] * bh[j];
            }
        }
    }
    for (int i = 0; i < 8; i++) {
        int rr = ty * 8 + i;
        if (rr >= rvi) break;
        float* cp0 = &Gb[(size_t)(r0 + rr) * TT + c0 + tx * 4];
        float4 cv0 = *reinterpret_cast<float4*>(cp0);
        cv0.x -= acc[i][0]; cv0.y -= acc[i][1]; cv0.z -= acc[i][2]; cv0.w -= acc[i][3];
        *reinterpret_cast<float4*>(cp0) = cv0;
        float* cp1 = cp0 + 64;
        float4 cv1 = *reinterpret_cast<float4*>(cp1);
        cv1.x -= acc[i][4]; cv1.y -= acc[i][5]; cv1.z -= acc[i][6]; cv1.w -= acc[i][7];
        *reinterpret_cast<float4*>(cp1) = cv1;
    }
}

// ---------------- fused alpha solve: z = L^{-1}(y-c), alpha = L^{-T} z ----------------
__global__ __launch_bounds__(64) void k_solve(const float* __restrict__ A,
                                              const float* __restrict__ values,
                                              const float* __restrict__ mc,
                                              float* __restrict__ abuf, int b0) {
    int bz = blockIdx.x; int b = b0 + bz;
    const float* Ab = A + (size_t)bz * TT * TT;
    __shared__ float zl[TT];
    __shared__ float Ld[NB][NB + 1];
    __shared__ float invd[NB];
    int t = threadIdx.x;
    float c0 = mc[0];
    for (int i = t; i < TT; i += 64) zl[i] = values[b * TT + i] - c0;
    for (int k = 0; k < NSTEPS; k++) {
        int kb = k * NB;
        __syncthreads();
        for (int l = 0; l < NB; l++) Ld[l][t] = Ab[(size_t)(kb + l) * TT + kb + t];
        __syncthreads();
        invd[t] = 1.0f / Ld[t][t];
        __syncthreads();
        for (int j = 0; j < NB; j++) {
            if (t == j) zl[kb + j] *= invd[j];
            __syncthreads();
            if (t > j) zl[kb + t] -= Ld[t][j] * zl[kb + j];
        }
        __syncthreads();
        for (int r = kb + NB + t; r < TT; r += 64) {
            float acc = 0.f;
            for (int c = 0; c < NB; c++) acc += Ab[(size_t)r * TT + kb + c] * zl[kb + c];
            zl[r] -= acc;
        }
    }
    for (int k = NSTEPS - 1; k >= 0; k--) {
        int kb = k * NB;
        __syncthreads();
        for (int l = 0; l < NB; l++) Ld[l][t] = Ab[(size_t)(kb + l) * TT + kb + t];
        __syncthreads();
        invd[t] = 1.0f / Ld[t][t];
        __syncthreads();
        for (int j = NB - 1; j >= 0; j--) {
            if (t == j) zl[kb + j] *= invd[j];
            __syncthreads();
            if (t < j) zl[kb + t] -= Ld[j][t] * zl[kb + j];
        }
        __syncthreads();
        for (int i = t; i < kb; i += 64) {
            float acc = 0.f;
            for (int j = 0; j < NB; j++) acc += Ab[(size_t)(kb + j) * TT + i] * zl[kb + j];
            zl[i] -= acc;
        }
    }
    __syncthreads();
    for (int i = t; i < TT; i += 64) abuf[b * TT + i] = zl[i];
}

// ---------------- mean = c + G^T alpha ----------------
__global__ __launch_bounds__(256) void k_mean(const float* __restrict__ G,
                                              const float* __restrict__ abuf,
                                              const float* __restrict__ mc,
                                              float* __restrict__ meanb, int b0) {
    int bz = blockIdx.y; int b = b0 + bz;
    const float* Gb = G + (size_t)bz * TT * TT;
    int i = blockIdx.x * 256 + threadIdx.x;
    float acc = 0.f;
    for (int j = 0; j < TT; j++) acc += Gb[(size_t)j * TT + i] * abuf[b * TT + j];
    meanb[b * TT + i] = mc[0] + acc;
}

// ---------------- cov = Kss - V^T V + JIT*I : 128x128 tiles, XCD-pinned ----------------
__global__ __launch_bounds__(256) void k_cov128(const float* __restrict__ G,
                                                const float* __restrict__ xs,
                                                const int* __restrict__ ite,
                                                const float* __restrict__ lsp,
                                                const float* __restrict__ Bt,
                                                float* __restrict__ A, int b0, int bc) {
    int lin = blockIdx.x;
    int slot = lin & 7, tau = lin >> 3;
    int beta = ((slot - 4 * (tau & 1)) & 7) + (blockIdx.y << 3);
    if (beta >= bc) return;
    int ti, tj; tri_map(tau, ti, tj);
    int b = b0 + beta;
    const float* Gb = G + (size_t)beta * TT * TT;
    float* Ab = A + (size_t)beta * TT * TT;
    int i0 = ti * 128, j0 = tj * 128;
    __shared__ __align__(16) float Va[32][132];
    __shared__ __align__(16) float Vb[32][132];
    __shared__ float sxi[128], sxj[128], Btl[289];
    __shared__ int sei[128], sej[128];
    int t = threadIdx.x, tx = t & 15, ty = t >> 4;
    if (t < 128) { sxi[t] = xs[b * TT + i0 + t]; sei[t] = ite[b * TT + i0 + t]; }
    else { int u = t - 128; sxj[u] = xs[b * TT + j0 + u]; sej[u] = ite[b * TT + j0 + u]; }
    for (int e = t; e < 289; e += 256) Btl[e] = Bt[e];
    float acc[8][8] = {};
    for (int k0 = 0; k0 < TT; k0 += 32) {
        __syncthreads();
        for (int l = 0; l < 4; l++) {
            int f = l * 256 + t;
            int kr = f >> 5, cc4 = (f & 31) * 4;
            *reinterpret_cast<float4*>(&Va[kr][cc4]) =
                *reinterpret_cast<const float4*>(&Gb[(size_t)(k0 + kr) * TT + i0 + cc4]);
            *reinterpret_cast<float4*>(&Vb[kr][cc4]) =
                *reinterpret_cast<const float4*>(&Gb[(size_t)(k0 + kr) * TT + j0 + cc4]);
        }
        __syncthreads();
#pragma unroll 4
        for (int p = 0; p < 32; p++) {
            float4 a0 = *reinterpret_cast<const float4*>(&Va[p][ty * 8]);
            float4 a1 = *reinterpret_cast<const float4*>(&Va[p][ty * 8 + 4]);
            float4 b0 = *reinterpret_cast<const float4*>(&Vb[p][tx * 4]);
            float4 b1 = *reinterpret_cast<const float4*>(&Vb[p][tx * 4 + 64]);
            float aa[8] = {a0.x, a0.y, a0.z, a0.w, a1.x, a1.y, a1.z, a1.w};
            float bl[4] = {b0.x, b0.y, b0.z, b0.w};
            float bh[4] = {b1.x, b1.y, b1.z, b1.w};
            for (int i = 0; i < 8; i++) {
                for (int j = 0; j < 4; j++) acc[i][j] += aa[i] * bl[j];
                for (int j = 0; j < 4; j++) acc[i][j + 4] += aa[i] * bh[j];
            }
        }
    }
    float invls = 1.0f / lsp[0];
    for (int i = 0; i < 8; i++) {
        int ri = ty * 8 + i; int gi = i0 + ri;
        float xi = sxi[ri]; int ci = sei[ri] * 17;
        float vo[8];
        for (int j = 0; j < 4; j++) {
            int rj = tx * 4 + j; int gj = j0 + rj;
            float d = (xi - sxj[rj]) * invls;
            float v = expf(-0.5f * d * d) * Btl[ci + sej[rj]] - acc[i][j];
            if (gi == gj) v += JIT;
            vo[j] = v;
        }
        for (int j = 0; j < 4; j++) {
            int rj = 64 + tx * 4 + j; int gj = j0 + rj;
            float d = (xi - sxj[rj]) * invls;
            float v = expf(-0.5f * d * d) * Btl[ci + sej[rj]] - acc[i][j + 4];
            if (gi == gj) v += JIT;
            vo[j + 4] = v;
        }
        float* cp = &Ab[(size_t)gi * TT + j0 + tx * 4];
        *reinterpret_cast<float4*>(cp) = make_float4(vo[0], vo[1], vo[2], vo[3]);
        *reinterpret_cast<float4*>(cp + 64) = make_float4(vo[4], vo[5], vo[6], vo[7]);
    }
}

// ---------------- P[c][j] = sum_{i>=j, ch(i)=c} Lstar[i][j] ----------------
__global__ __launch_bounds__(256) void k_P(const float* __restrict__ A,
                                           const int* __restrict__ ite,
                                           float* __restrict__ P, int b0) {
    int bz = blockIdx.y; int b = b0 + bz;
    const float* Ab = A + (size_t)bz * TT * TT;
    __shared__ int chl[TT];
    __shared__ float accl[CH * 256];
    int t = threadIdx.x;
    for (int i = t; i < TT; i += 256) chl[i] = ite[b * TT + i];
    for (int c = 0; c < CH; c++) accl[c * 256 + t] = 0.f;
    __syncthreads();
    int j0 = blockIdx.x * 256;
    int j = j0 + t;
    for (int i = j0; i < TT; i++) {
        float v = Ab[(size_t)i * TT + j];
        if (i >= j) accl[chl[i] * 256 + t] += v;
    }
    for (int c = 0; c < CH; c++) P[((size_t)b * CH + c) * TT + j] = accl[c * 256 + t];
}

// ---------------- msum[c] = sum_{ch(i)=c} mean[i] ----------------
__global__ __launch_bounds__(64) void k_msum(const float* __restrict__ meanb,
                                             const int* __restrict__ ite,
                                             float* __restrict__ msum, int b0) {
    int bz = blockIdx.x; int b = b0 + bz;
    __shared__ float pacc[CH][65];
    int t = threadIdx.x;
    for (int c = 0; c < CH; c++) pacc[c][t] = 0.f;
    __syncthreads();
    for (int i = t; i < TT; i += 64) pacc[ite[b * TT + i]][t] += meanb[b * TT + i];
    __syncthreads();
    if (t < CH) {
        float s = 0.f;
        for (int u = 0; u < 64; u++) s += pacc[t][u];
        msum[b * CH + t] = s;
    }
}

// ---------------- feat + classifier head ----------------
__global__ __launch_bounds__(256) void k_featout(const float* __restrict__ P,
                                                 const float* __restrict__ msum,
                                                 const float* __restrict__ eps,
                                                 const float* __restrict__ Wc,
                                                 const float* __restrict__ bc_,
                                                 float* __restrict__ out, int b0, int Btot) {
    int s = blockIdx.x; int b = b0 + blockIdx.y;
    __shared__ float el[TT];
    __shared__ float part[256];
    __shared__ float featl[CH];
    int t = threadIdx.x;
    for (int i = t; i < TT; i += 256) el[i] = eps[((size_t)s * Btot + b) * TT + i];
    __syncthreads();
    int c = t >> 4, seg = t & 15;
    float acc = 0.f;
    const float* Pr = &P[((size_t)b * CH + c) * TT + seg * 64];
    for (int j = 0; j < 64; j++) acc += Pr[j] * el[seg * 64 + j];
    part[t] = acc;
    __syncthreads();
    if (t < CH) {
        float s2 = msum[b * CH + t];
        for (int g = 0; g < 16; g++) s2 += part[t * 16 + g];
        featl[t] = s2 * (1.0f / 64.0f);
    }
    __syncthreads();
    if (t < NCLS) {
        float o = bc_[t];
        for (int c2 = 0; c2 < CH; c2++) o += featl[c2] * Wc[c2 * NCLS + t];
        out[((size_t)s * Btot + b) * NCLS + t] = o;
    }
}

extern "C" void kernel_launch(void* const* d_in, const int* in_sizes, int n_in,
                              void* d_out, int out_size, void* d_ws, size_t ws_size,
                              hipStream_t stream) {
    const float* inputs       = (const float*)d_in[0];
    const float* values       = (const float*)d_in[1];
    const float* test_inputs  = (const float*)d_in[2];
    const float* eps          = (const float*)d_in[3];
    const float* mc           = (const float*)d_in[4];
    const float* ls           = (const float*)d_in[5];
    const float* noise        = (const float*)d_in[6];
    const float* W_task       = (const float*)d_in[7];
    const float* v_task       = (const float*)d_in[8];
    const float* W_clf        = (const float*)d_in[9];
    const float* b_clf        = (const float*)d_in[10];
    const int*   indices      = (const int*)d_in[11];
    const int*   test_indices = (const int*)d_in[12];
    float* out = (float*)d_out;

    int Btot = in_sizes[1] / TT;   // 32

    float* ws = (float*)d_ws;
    size_t off = 0;
    float* Bt    = ws + off; off += 512;
    float* abuf  = ws + off; off += (size_t)Btot * TT;
    float* meanb = ws + off; off += (size_t)Btot * TT;
    float* Pb    = ws + off; off += (size_t)Btot * CH * TT;
    float* msum  = ws + off; off += (size_t)Btot * CH;
    off = (off + 63) & ~(size_t)63;

    size_t avail = (ws_size / 4 > off) ? (ws_size / 4 - off) : 0;
    size_t per = 2 * (size_t)TT * TT;
    int chunk = (int)(avail / per);
    if (chunk < 1) chunk = 1;
    if (chunk > Btot) chunk = Btot;
    float* bigA = ws + off;
    float* bigG = bigA + (size_t)chunk * TT * TT;

    k_btask<<<1, 256, 0, stream>>>(W_task, v_task, Bt);

    for (int b0 = 0; b0 < Btot; b0 += chunk) {
        int bcc = chunk; if (b0 + bcc > Btot) bcc = Btot - b0;
        int by = (bcc + 7) / 8;

        // ---- Kxx and its Cholesky ----
        k_build_kxx<<<dim3(8, 8, bcc), 256, 0, stream>>>(inputs, indices, ls, noise, Bt, bigA, b0);
        for (int k = 0; k < NSTEPS; k++) {
            int m = NSTEPS - 1 - k;
            k_chol_step<<<dim3(m + 1, bcc), 64, 0, stream>>>(bigA, k);
            if (m > 0) {
                int nt = (NB * m + 127) / 128;
                int tiles = nt * (nt + 1) / 2;
                k_syrk128<<<dim3(tiles * 8, by), 256, 0, stream>>>(bigA, k, bcc);
            }
        }
        // ---- alpha = Kxx^{-1}(y-c) ----
        k_solve<<<bcc, 64, 0, stream>>>(bigA, values, mc, abuf, b0);
        // ---- G = Ksx^T, mean ----
        k_build_g<<<dim3(8, 8, bcc), 256, 0, stream>>>(test_inputs, inputs, test_indices, indices, ls, Bt, bigG, b0);
        k_mean<<<dim3(4, bcc), 256, 0, stream>>>(bigG, abuf, mc, meanb, b0);
        // ---- V = L^{-1} G (in place) ----
        for (int k = 0; k < NSTEPS; k++) {
            k_trsm_diag<<<dim3(4, bcc), 256, 0, stream>>>(bigA, bigG, k);
            int m = NSTEPS - 1 - k;
            if (m > 0) {
                int nt = (NB * m + 127) / 128;
                k_gemm_update128<<<dim3(nt * 8 * 8, by), 256, 0, stream>>>(bigA, bigG, k, bcc);
            }
        }
        // ---- cov -> A, chol(cov) ----
        k_cov128<<<dim3(36 * 8, by), 256, 0, stream>>>(bigG, test_inputs, test_indices, ls, Bt, bigA, b0, bcc);
        for (int k = 0; k < NSTEPS; k++) {
            int m = NSTEPS - 1 - k;
            k_chol_step<<<dim3(m + 1, bcc), 64, 0, stream>>>(bigA, k);
            if (m > 0) {
                int nt = (NB * m + 127) / 128;
                int tiles = nt * (nt + 1) / 2;
                k_syrk128<<<dim3(tiles * 8, by), 256, 0, stream>>>(bigA, k, bcc);
            }
        }
        // ---- pooled sampling + classifier ----
        k_P<<<dim3(4, bcc), 256, 0, stream>>>(bigA, test_indices, Pb, b0);
        k_msum<<<bcc, 64, 0, stream>>>(meanb, test_indices, msum, b0);
        k_featout<<<dim3(SMC, bcc), 256, 0, stream>>>(Pb, msum, eps, W_clf, b_clf, out, b0, Btot);
    }
}